// Round 12
// baseline (179.347 us; speedup 1.0000x reference)
//
#include <hip/hip_runtime.h>

// SimCLR fused pipeline, round 12.
// sim: NSPLIT=64 (2048 blocks = 8/CU block supply) with `#pragma unroll 1`
//      to keep the 8-iter loop ROLLED (r10's identical config without the
//      pragma got fully unrolled -> VGPR 128 -> regression). VGPR target ~84.
// convert_w: weights only (r11's h pre-conversion was a measured +6us loss).
// gemm1: fp32-h in-register cvt loader (r9-proven), (128,8) grid, bf16 Y out.
// gemm2: r11 structure (8 waves x 16x16, dist-1 prefetch, bf16 Y in).

#define NB   4096
#define DIN  192
#define DHID 512
#define DOUT 128
#define N2   8192   // 2*NB
#define NSPLIT 64   // sim col-splits; 128 cols per block
#define SIM_ITERS 8

typedef short short8 __attribute__((ext_vector_type(8)));   // 8 bf16 (4 VGPRs)
typedef float floatx4 __attribute__((ext_vector_type(4)));  // MFMA C/D frag

__device__ inline float fast_exp2(float x) {
#if __has_builtin(__builtin_amdgcn_exp2f)
    return __builtin_amdgcn_exp2f(x);
#else
    return exp2f(x);
#endif
}

__device__ inline unsigned short bf16_rne(float x) {
    unsigned int u = __float_as_uint(x);
    return (unsigned short)((u + 0x7fffu + ((u >> 16) & 1u)) >> 16);
}

// ---------------- convert W1, W2 -> bf16 ------------------------------------
__global__ __launch_bounds__(256) void convert_w(
    const float* __restrict__ W1, const float* __restrict__ W2,
    unsigned short* __restrict__ W1b, unsigned short* __restrict__ W2b)
{
    const int NW1 = DHID * DIN / 4;   // 24576 float4
    const int NW2 = DOUT * DHID / 4;  // 16384 float4
    int id = blockIdx.x * 256 + threadIdx.x;
    const float* src; unsigned short* dst; int off;
    if (id < NW1)            { src = W1; dst = W1b; off = id; }
    else if (id < NW1 + NW2) { src = W2; dst = W2b; off = id - NW1; }
    else return;
    float4 x = ((const float4*)src)[off];
    unsigned int p0 = bf16_rne(x.x) | ((unsigned int)bf16_rne(x.y) << 16);
    unsigned int p1 = bf16_rne(x.z) | ((unsigned int)bf16_rne(x.w) << 16);
    ((uint2*)dst)[off] = make_uint2(p0, p1);
}

// ------- GEMM1 (bf16 MFMA): Ybf = [h1;h2] @ W1^T + b1, fused BN col-sums ---
// grid (128 m-blocks of 64 rows, 8 n-splits of 64 cols), 256 thr (4 waves).
// Wave: 16 rows x 64 cols (4 nt), K=192 (6 kc). h loaded fp32, cvt in-reg.
__global__ __launch_bounds__(256) void gemm1_mfma(
    const float* __restrict__ h1, const float* __restrict__ h2,
    const unsigned short* __restrict__ W1b, const float* __restrict__ b1,
    unsigned short* __restrict__ Ybf,
    float* __restrict__ psumc, float* __restrict__ psqc)
{
    const int t = threadIdx.x;
    const int wave = t >> 6, lane = t & 63;
    const int quad = lane >> 4, l15 = lane & 15;
    const int mb = blockIdx.x;
    const int m0 = mb * 64 + wave * 16;
    const int n0 = blockIdx.y * 64;
    const int v  = (mb >= 64);

    short8 a[6];
    {
        int row = m0 + l15;
        const float* hsrc = (row < NB) ? (h1 + (size_t)row * DIN)
                                       : (h2 + (size_t)(row - NB) * DIN);
        #pragma unroll
        for (int kc = 0; kc < 6; ++kc) {
            const float4* p = (const float4*)(hsrc + kc * 32 + quad * 8);
            float4 x0 = p[0], x1 = p[1];
            float xs[8] = {x0.x,x0.y,x0.z,x0.w,x1.x,x1.y,x1.z,x1.w};
            #pragma unroll
            for (int j = 0; j < 8; ++j) a[kc][j] = (short)bf16_rne(xs[j]);
        }
    }

    #pragma unroll
    for (int nt = 0; nt < 4; ++nt) {
        const int col = n0 + nt * 16 + l15;
        const short8* bptr = (const short8*)(W1b + (size_t)col * DIN + quad * 8);
        short8 b[6];
        #pragma unroll
        for (int kc = 0; kc < 6; ++kc) b[kc] = bptr[kc * 4];
        floatx4 acc = {0.f,0.f,0.f,0.f};
        #pragma unroll
        for (int kc = 0; kc < 6; ++kc)
            acc = __builtin_amdgcn_mfma_f32_16x16x32_bf16(a[kc], b[kc], acc, 0,0,0);
        const float bias = b1[col];
        float cs = 0.f, cq = 0.f;
        #pragma unroll
        for (int reg = 0; reg < 4; ++reg) {
            float y = acc[reg] + bias;
            int row = m0 + quad * 4 + reg;
            Ybf[(size_t)row * DHID + col] = bf16_rne(y);
            cs += y; cq += y * y;
        }
        cs += __shfl_xor(cs, 16); cs += __shfl_xor(cs, 32);
        cq += __shfl_xor(cq, 16); cq += __shfl_xor(cq, 32);
        if (quad == 0) {
            atomicAdd(psumc + v * DHID + col, cs);
            atomicAdd(psqc  + v * DHID + col, cq);
        }
    }
}

#define ZSCALE 1.6986436f   // sqrt(2*log2(e)); Zb = z*ZSCALE so dot = exp2 arg

// ---- GEMM2 (bf16 MFMA): z = relu(bn(Y)) @ W2^T + b2, L2-norm --------------
// 8 waves x (16 rows x 16 cols), grid 512 x 512 thr = 4096 waves (4/SIMD).
// Rolled 16-iter K-loop with dist-1 prefetch of Y (1 uint4) and W2 (1 short8).
// bn-finalize fused in prologue; 8-wave sq combine via LDS.
__global__ __launch_bounds__(512) void gemm2_mfma(
    const unsigned short* __restrict__ Ybf, const unsigned short* __restrict__ W2b,
    const float* __restrict__ psumc, const float* __restrict__ psqc,
    const float* __restrict__ gamma, const float* __restrict__ beta,
    const float* __restrict__ b2,
    unsigned short* __restrict__ Zb, float* __restrict__ outz)
{
    __shared__ float sc_sh[DHID], sh_sh[DHID];
    __shared__ float sq_lds[8][16];
    const int t = threadIdx.x;
    const int wave = t >> 6, lane = t & 63;
    const int quad = lane >> 4, l15 = lane & 15;
    const int mtbase = blockIdx.x * 16;
    const int v = (mtbase >= NB);
    const int col = wave * 16 + l15;

    {   // bn finalize: 512 threads cover 512 cols
        int c = t;
        float mean = psumc[v * DHID + c] * (1.0f / NB);
        float var  = psqc [v * DHID + c] * (1.0f / NB) - mean * mean;
        float rstd = rsqrtf(var + 1e-5f);
        float scv = gamma[c] * rstd;
        sc_sh[c] = scv;
        sh_sh[c] = beta[c] - mean * scv;
    }
    __syncthreads();

    const unsigned short* yrow = Ybf + (size_t)(mtbase + l15) * DHID + quad * 8;
    const unsigned short* wcol = W2b + (size_t)col * DHID + quad * 8;

    uint4 ycur = *(const uint4*)yrow;
    short8 bcur = *(const short8*)wcol;
    floatx4 acc = {0.f, 0.f, 0.f, 0.f};

    #pragma unroll 1
    for (int kc = 0; kc < 16; ++kc) {
        const int kn = (kc + 1) & 15;         // wraps on last iter (unused)
        uint4 ynext = *(const uint4*)(yrow + kn * 32);
        short8 bnext = *(const short8*)(wcol + kn * 32);

        const int k = kc * 32 + quad * 8;
        const float4 s0 = *(const float4*)&sc_sh[k], s1 = *(const float4*)&sc_sh[k + 4];
        const float4 h0 = *(const float4*)&sh_sh[k], h1v = *(const float4*)&sh_sh[k + 4];
        const unsigned int yw[4] = {ycur.x, ycur.y, ycur.z, ycur.w};
        float xs[8];
        #pragma unroll
        for (int c2 = 0; c2 < 4; ++c2) {
            xs[c2 * 2]     = __uint_as_float(yw[c2] << 16);
            xs[c2 * 2 + 1] = __uint_as_float(yw[c2] & 0xffff0000u);
        }
        const float ss[8] = {s0.x,s0.y,s0.z,s0.w,s1.x,s1.y,s1.z,s1.w};
        const float hh[8] = {h0.x,h0.y,h0.z,h0.w,h1v.x,h1v.y,h1v.z,h1v.w};
        short8 afr;
        #pragma unroll
        for (int j = 0; j < 8; ++j)
            afr[j] = (short)bf16_rne(fmaxf(xs[j] * ss[j] + hh[j], 0.f));
        acc = __builtin_amdgcn_mfma_f32_16x16x32_bf16(afr, bcur, acc, 0,0,0);
        ycur = ynext; bcur = bnext;
    }

    const float bias = b2[col];
    float zv[4];
    #pragma unroll
    for (int reg = 0; reg < 4; ++reg) {
        zv[reg] = acc[reg] + bias;
        float q = zv[reg] * zv[reg];
        q += __shfl_xor(q, 1); q += __shfl_xor(q, 2);
        q += __shfl_xor(q, 4); q += __shfl_xor(q, 8);
        if (l15 == 0) sq_lds[wave][quad * 4 + reg] = q;
    }
    __syncthreads();
    #pragma unroll
    for (int reg = 0; reg < 4; ++reg) {
        float tot = 0.f;
        #pragma unroll
        for (int w = 0; w < 8; ++w) tot += sq_lds[w][quad * 4 + reg];
        float inv = 1.0f / fmaxf(sqrtf(tot), 1e-12f);
        const int row = mtbase + quad * 4 + reg;
        float z = zv[reg] * inv;
        outz[(size_t)row * DOUT + col] = z;
        Zb[(size_t)row * DOUT + col] = bf16_rne(z * ZSCALE);
    }
}

// ---- sim: psum_row = sum_cols exp2(Zb . Zb^T)  (diag included; subtracted
// in row_finalize). Wave owns 64 rows (4 A-tiles in regs); ROLLED 8-iter loop
// (#pragma unroll 1 -- critical: full unroll costs VGPR 128 and -27%, r10);
// dist-1 double-buffered 16-col B-tile; 16 MFMA + 16 exp per iter.
// grid (32, NSPLIT=64) = 2048 blocks (8/CU) x 256 thr.
__global__ __launch_bounds__(256) void sim_mfma(
    const unsigned short* __restrict__ Zb, float* __restrict__ psum)
{
    const int t = threadIdx.x;
    const int wave = t >> 6, lane = t & 63;
    const int quad = lane >> 4, l15 = lane & 15;
    const int mbase = blockIdx.x * 256 + wave * 64;   // 64 rows per wave
    const int cs = blockIdx.y;                        // 0..NSPLIT-1
    const int cbase = cs * (N2 / NSPLIT);             // 128-col slice

    short8 a[4][4];
    #pragma unroll
    for (int at = 0; at < 4; ++at) {
        const short8* zra = (const short8*)(Zb + (size_t)(mbase + at * 16 + l15) * DOUT + quad * 8);
        #pragma unroll
        for (int kc = 0; kc < 4; ++kc) a[at][kc] = zra[kc * 4];
    }

    float rs[4][4];
    #pragma unroll
    for (int at = 0; at < 4; ++at)
        #pragma unroll
        for (int r = 0; r < 4; ++r) rs[at][r] = 0.f;

    short8 bcur[4], bnext[4];
    {
        const short8* zb = (const short8*)(Zb + (size_t)(cbase + l15) * DOUT + quad * 8);
        #pragma unroll
        for (int kc = 0; kc < 4; ++kc) bcur[kc] = zb[kc * 4];
    }

    #pragma unroll 1
    for (int nt = 0; nt < SIM_ITERS; ++nt) {
        const int cn = cbase + ((nt + 1) & (SIM_ITERS - 1)) * 16;
        const short8* zbn = (const short8*)(Zb + (size_t)(cn + l15) * DOUT + quad * 8);
        #pragma unroll
        for (int kc = 0; kc < 4; ++kc) bnext[kc] = zbn[kc * 4];

        floatx4 acc[4] = {{0.f,0.f,0.f,0.f},{0.f,0.f,0.f,0.f},
                          {0.f,0.f,0.f,0.f},{0.f,0.f,0.f,0.f}};
        #pragma unroll
        for (int kc = 0; kc < 4; ++kc)
            #pragma unroll
            for (int at = 0; at < 4; ++at)
                acc[at] = __builtin_amdgcn_mfma_f32_16x16x32_bf16(a[at][kc], bcur[kc], acc[at], 0, 0, 0);

        #pragma unroll
        for (int at = 0; at < 4; ++at)
            #pragma unroll
            for (int r = 0; r < 4; ++r)
                rs[at][r] += fast_exp2(acc[at][r]);

        #pragma unroll
        for (int kc = 0; kc < 4; ++kc) bcur[kc] = bnext[kc];
    }

    #pragma unroll
    for (int at = 0; at < 4; ++at) {
        const int gi0 = mbase + at * 16 + quad * 4;
        #pragma unroll
        for (int r = 0; r < 4; ++r) {
            float s = rs[at][r];
            s += __shfl_xor(s, 1);
            s += __shfl_xor(s, 2);
            s += __shfl_xor(s, 4);
            s += __shfl_xor(s, 8);
            if (l15 == 0) psum[(size_t)cs * N2 + gi0 + r] = s;
        }
    }
}

// ---- per-row lse - pos, minus diag term; block-reduce -> atomic loss ------
__global__ __launch_bounds__(256) void row_finalize(
    const unsigned short* __restrict__ Zb, const float* __restrict__ psum,
    float* __restrict__ out)
{
    int i = blockIdx.x * 256 + threadIdx.x;
    float s = 0.f;
    for (int cs = 0; cs < NSPLIT; ++cs) s += psum[(size_t)cs * N2 + i];
    int k = i & (NB - 1);
    const uint4* z1 = (const uint4*)(Zb + (size_t)k * DOUT);
    const uint4* z2 = (const uint4*)(Zb + (size_t)(k + NB) * DOUT);
    float d12 = 0.f, d11 = 0.f, d22 = 0.f;
    #pragma unroll
    for (int q = 0; q < 16; ++q) {
        uint4 a = z1[q], bqq = z2[q];
        const unsigned int aw[4] = {a.x, a.y, a.z, a.w};
        const unsigned int bw[4] = {bqq.x, bqq.y, bqq.z, bqq.w};
        #pragma unroll
        for (int c = 0; c < 4; ++c) {
            float alo = __uint_as_float(aw[c] << 16);
            float ahi = __uint_as_float(aw[c] & 0xffff0000u);
            float blo = __uint_as_float(bw[c] << 16);
            float bhi = __uint_as_float(bw[c] & 0xffff0000u);
            d12 += alo * blo + ahi * bhi;
            d11 += alo * alo + ahi * ahi;
            d22 += blo * blo + bhi * bhi;
        }
    }
    float dself = (i < NB) ? d11 : d22;
    // Zb is scaled: dot' = 2*log2(e)*dot => 2*dot = dot'*ln2; diag = exp2(dot')
    float rowval = logf(s - fast_exp2(dself)) - d12 * 0.69314718f;

    float r = rowval;
    r += __shfl_xor(r, 1);  r += __shfl_xor(r, 2);  r += __shfl_xor(r, 4);
    r += __shfl_xor(r, 8);  r += __shfl_xor(r, 16); r += __shfl_xor(r, 32);
    __shared__ float wsr[4];
    int lane = threadIdx.x & 63, w = threadIdx.x >> 6;
    if (lane == 0) wsr[w] = r;
    __syncthreads();
    if (threadIdx.x == 0)
        atomicAdd(out, (wsr[0] + wsr[1] + wsr[2] + wsr[3]) * (1.0f / N2));
}

extern "C" void kernel_launch(void* const* d_in, const int* in_sizes, int n_in,
                              void* d_out, int out_size, void* d_ws, size_t ws_size,
                              hipStream_t stream)
{
    const float* h1    = (const float*)d_in[0];
    const float* h2    = (const float*)d_in[1];
    const float* W1    = (const float*)d_in[2];
    const float* b1    = (const float*)d_in[3];
    const float* gamma = (const float*)d_in[4];
    const float* beta  = (const float*)d_in[5];
    const float* W2    = (const float*)d_in[6];
    const float* b2    = (const float*)d_in[7];
    float* out = (float*)d_out;

    float* ws      = (float*)d_ws;
    float* psumc   = ws;                            // 1024 f
    float* psqc    = psumc + 1024;                  // 1024 f
    unsigned short* W1b = (unsigned short*)(psqc + 1024);   // 98304 us
    unsigned short* W2b = W1b + DHID * DIN;         // 65536 us
    unsigned short* Ybf = W2b + DOUT * DHID;        // 8192*512 us = 8MB
    float* psum    = (float*)(Ybf + (size_t)N2 * DHID); // 64*8192 f = 2MB
    unsigned short* Zb = (unsigned short*)(psum + (size_t)NSPLIT * N2); // 2MB
    // total ~12.6 MB

    hipMemsetAsync(psumc, 0, 2048 * sizeof(float), stream);  // psumc+psqc
    hipMemsetAsync(out, 0, sizeof(float), stream);           // loss accumulator

    convert_w   <<<dim3(160),        256, 0, stream>>>(W1, W2, W1b, W2b);
    gemm1_mfma  <<<dim3(128, 8),     256, 0, stream>>>(h1, h2, W1b, b1, Ybf, psumc, psqc);
    gemm2_mfma  <<<dim3(512),        512, 0, stream>>>(Ybf, W2b, psumc, psqc, gamma, beta, b2, Zb, out + 1);
    sim_mfma    <<<dim3(32, NSPLIT), 256, 0, stream>>>(Zb, psum);
    row_finalize<<<dim3(32),         256, 0, stream>>>(Zb, psum, out);
}

// Round 13
// 167.100 us; speedup vs baseline: 1.0733x; 1.0733x over previous
//
#include <hip/hip_runtime.h>

// SimCLR fused pipeline, round 13.
// sim: r11-exact math (NSPLIT 32, 16 rolled iters, dist-1 dbuf) but 128-thread
//      blocks (2 waves), grid (64,32) -- probes whether the ~8 waves/CU
//      occupancy cap is block-packing granularity.
// gemm2: split-K x2 -- 16 waves/block (1024 thr), K halves per wave pair,
//      LDS combine; 8192 waves = 8/SIMD, per-wave chain halves.
// convert_w: absorbs psumc/psqc/out zeroing (7 launches -> 5).
// gemm1: r12 version (unchanged).

#define NB   4096
#define DIN  192
#define DHID 512
#define DOUT 128
#define N2   8192   // 2*NB
#define NSPLIT 32   // sim col-splits; 256 cols per block
#define SIM_ITERS 16

typedef short short8 __attribute__((ext_vector_type(8)));   // 8 bf16 (4 VGPRs)
typedef float floatx4 __attribute__((ext_vector_type(4)));  // MFMA C/D frag

__device__ inline float fast_exp2(float x) {
#if __has_builtin(__builtin_amdgcn_exp2f)
    return __builtin_amdgcn_exp2f(x);
#else
    return exp2f(x);
#endif
}

__device__ inline unsigned short bf16_rne(float x) {
    unsigned int u = __float_as_uint(x);
    return (unsigned short)((u + 0x7fffu + ((u >> 16) & 1u)) >> 16);
}

// ------- convert W1, W2 -> bf16; block 0 also zeroes psumc/psqc/out --------
__global__ __launch_bounds__(256) void convert_w(
    const float* __restrict__ W1, const float* __restrict__ W2,
    unsigned short* __restrict__ W1b, unsigned short* __restrict__ W2b,
    float* __restrict__ psumc /* +psqc contiguous: 2048 floats */,
    float* __restrict__ out)
{
    const int NW1 = DHID * DIN / 4;   // 24576 float4
    const int NW2 = DOUT * DHID / 4;  // 16384 float4
    int id = blockIdx.x * 256 + threadIdx.x;
    if (blockIdx.x == 0) {
        for (int i = threadIdx.x; i < 2048; i += 256) psumc[i] = 0.f;
        if (threadIdx.x == 0) out[0] = 0.f;
    }
    const float* src; unsigned short* dst; int off;
    if (id < NW1)            { src = W1; dst = W1b; off = id; }
    else if (id < NW1 + NW2) { src = W2; dst = W2b; off = id - NW1; }
    else return;
    float4 x = ((const float4*)src)[off];
    unsigned int p0 = bf16_rne(x.x) | ((unsigned int)bf16_rne(x.y) << 16);
    unsigned int p1 = bf16_rne(x.z) | ((unsigned int)bf16_rne(x.w) << 16);
    ((uint2*)dst)[off] = make_uint2(p0, p1);
}

// ------- GEMM1 (bf16 MFMA): Ybf = [h1;h2] @ W1^T + b1, fused BN col-sums ---
// grid (128 m-blocks of 64 rows, 8 n-splits of 64 cols), 256 thr (4 waves).
__global__ __launch_bounds__(256) void gemm1_mfma(
    const float* __restrict__ h1, const float* __restrict__ h2,
    const unsigned short* __restrict__ W1b, const float* __restrict__ b1,
    unsigned short* __restrict__ Ybf,
    float* __restrict__ psumc, float* __restrict__ psqc)
{
    const int t = threadIdx.x;
    const int wave = t >> 6, lane = t & 63;
    const int quad = lane >> 4, l15 = lane & 15;
    const int mb = blockIdx.x;
    const int m0 = mb * 64 + wave * 16;
    const int n0 = blockIdx.y * 64;
    const int v  = (mb >= 64);

    short8 a[6];
    {
        int row = m0 + l15;
        const float* hsrc = (row < NB) ? (h1 + (size_t)row * DIN)
                                       : (h2 + (size_t)(row - NB) * DIN);
        #pragma unroll
        for (int kc = 0; kc < 6; ++kc) {
            const float4* p = (const float4*)(hsrc + kc * 32 + quad * 8);
            float4 x0 = p[0], x1 = p[1];
            float xs[8] = {x0.x,x0.y,x0.z,x0.w,x1.x,x1.y,x1.z,x1.w};
            #pragma unroll
            for (int j = 0; j < 8; ++j) a[kc][j] = (short)bf16_rne(xs[j]);
        }
    }

    #pragma unroll
    for (int nt = 0; nt < 4; ++nt) {
        const int col = n0 + nt * 16 + l15;
        const short8* bptr = (const short8*)(W1b + (size_t)col * DIN + quad * 8);
        short8 b[6];
        #pragma unroll
        for (int kc = 0; kc < 6; ++kc) b[kc] = bptr[kc * 4];
        floatx4 acc = {0.f,0.f,0.f,0.f};
        #pragma unroll
        for (int kc = 0; kc < 6; ++kc)
            acc = __builtin_amdgcn_mfma_f32_16x16x32_bf16(a[kc], b[kc], acc, 0,0,0);
        const float bias = b1[col];
        float cs = 0.f, cq = 0.f;
        #pragma unroll
        for (int reg = 0; reg < 4; ++reg) {
            float y = acc[reg] + bias;
            int row = m0 + quad * 4 + reg;
            Ybf[(size_t)row * DHID + col] = bf16_rne(y);
            cs += y; cq += y * y;
        }
        cs += __shfl_xor(cs, 16); cs += __shfl_xor(cs, 32);
        cq += __shfl_xor(cq, 16); cq += __shfl_xor(cq, 32);
        if (quad == 0) {
            atomicAdd(psumc + v * DHID + col, cs);
            atomicAdd(psqc  + v * DHID + col, cq);
        }
    }
}

#define ZSCALE 1.6986436f   // sqrt(2*log2(e)); Zb = z*ZSCALE so dot = exp2 arg

// ---- GEMM2 (bf16 MFMA, split-K x2): z = relu(bn(Y)) @ W2^T + b2, L2-norm --
// 16 waves/block (1024 thr): wave w -> col-group (w&7), K-half (w>>3).
// Each wave: 8 rolled iters (dist-1 prefetch). K-halves combined via LDS.
// grid 512 x 1024 thr = 8192 waves (8/SIMD; 2 blocks/CU = full residency).
__global__ __launch_bounds__(1024) void gemm2_mfma(
    const unsigned short* __restrict__ Ybf, const unsigned short* __restrict__ W2b,
    const float* __restrict__ psumc, const float* __restrict__ psqc,
    const float* __restrict__ gamma, const float* __restrict__ beta,
    const float* __restrict__ b2,
    unsigned short* __restrict__ Zb, float* __restrict__ outz)
{
    __shared__ float sc_sh[DHID], sh_sh[DHID];
    __shared__ __align__(16) float acc_lds[8][64][4];   // upper-half partials
    __shared__ float sq_lds[8][16];
    const int t = threadIdx.x;
    const int wave = t >> 6, lane = t & 63;
    const int quad = lane >> 4, l15 = lane & 15;
    const int cg = wave & 7, kh = wave >> 3;
    const int mtbase = blockIdx.x * 16;
    const int v = (mtbase >= NB);
    const int col = cg * 16 + l15;

    if (t < DHID) {   // bn finalize: 512 threads cover 512 cols
        int c = t;
        float mean = psumc[v * DHID + c] * (1.0f / NB);
        float var  = psqc [v * DHID + c] * (1.0f / NB) - mean * mean;
        float rstd = rsqrtf(var + 1e-5f);
        float scv = gamma[c] * rstd;
        sc_sh[c] = scv;
        sh_sh[c] = beta[c] - mean * scv;
    }
    __syncthreads();

    const int kbase = kh * 8;   // this wave's 8 k-chunks
    const unsigned short* yrow = Ybf + (size_t)(mtbase + l15) * DHID + kbase * 32 + quad * 8;
    const unsigned short* wcol = W2b + (size_t)col * DHID + kbase * 32 + quad * 8;

    uint4 ycur = *(const uint4*)yrow;
    short8 bcur = *(const short8*)wcol;
    floatx4 acc = {0.f, 0.f, 0.f, 0.f};

    #pragma unroll 1
    for (int kc = 0; kc < 8; ++kc) {
        const int kn = (kc + 1) & 7;          // wraps on last iter (unused)
        uint4 ynext = *(const uint4*)(yrow + kn * 32);
        short8 bnext = *(const short8*)(wcol + kn * 32);

        const int k = (kbase + kc) * 32 + quad * 8;
        const float4 s0 = *(const float4*)&sc_sh[k], s1 = *(const float4*)&sc_sh[k + 4];
        const float4 h0 = *(const float4*)&sh_sh[k], h1v = *(const float4*)&sh_sh[k + 4];
        const unsigned int yw[4] = {ycur.x, ycur.y, ycur.z, ycur.w};
        float xs[8];
        #pragma unroll
        for (int c2 = 0; c2 < 4; ++c2) {
            xs[c2 * 2]     = __uint_as_float(yw[c2] << 16);
            xs[c2 * 2 + 1] = __uint_as_float(yw[c2] & 0xffff0000u);
        }
        const float ss[8] = {s0.x,s0.y,s0.z,s0.w,s1.x,s1.y,s1.z,s1.w};
        const float hh[8] = {h0.x,h0.y,h0.z,h0.w,h1v.x,h1v.y,h1v.z,h1v.w};
        short8 afr;
        #pragma unroll
        for (int j = 0; j < 8; ++j)
            afr[j] = (short)bf16_rne(fmaxf(xs[j] * ss[j] + hh[j], 0.f));
        acc = __builtin_amdgcn_mfma_f32_16x16x32_bf16(afr, bcur, acc, 0,0,0);
        ycur = ynext; bcur = bnext;
    }

    if (kh == 1) {   // upper half: publish partials
        #pragma unroll
        for (int reg = 0; reg < 4; ++reg) acc_lds[cg][lane][reg] = acc[reg];
    }
    __syncthreads();
    if (kh == 1) return;

    const float bias = b2[col];
    float zv[4];
    #pragma unroll
    for (int reg = 0; reg < 4; ++reg) {
        zv[reg] = acc[reg] + acc_lds[cg][lane][reg] + bias;
        float q = zv[reg] * zv[reg];
        q += __shfl_xor(q, 1); q += __shfl_xor(q, 2);
        q += __shfl_xor(q, 4); q += __shfl_xor(q, 8);
        if (l15 == 0) sq_lds[cg][quad * 4 + reg] = q;
    }
    __syncthreads();
    #pragma unroll
    for (int reg = 0; reg < 4; ++reg) {
        float tot = 0.f;
        #pragma unroll
        for (int w = 0; w < 8; ++w) tot += sq_lds[w][quad * 4 + reg];
        float inv = 1.0f / fmaxf(sqrtf(tot), 1e-12f);
        const int row = mtbase + quad * 4 + reg;
        float z = zv[reg] * inv;
        outz[(size_t)row * DOUT + col] = z;
        Zb[(size_t)row * DOUT + col] = bf16_rne(z * ZSCALE);
    }
}

// ---- sim: psum_row = sum_cols exp2(Zb . Zb^T)  (diag included; subtracted
// in row_finalize). r11-exact math; 128-thread blocks (2 waves of 64 rows),
// grid (64, NSPLIT=32). Rolled 16-iter loop (#pragma unroll 1), dist-1
// double-buffered 16-col B-tile; 16 MFMA + 16 exp per iter.
__global__ __launch_bounds__(128) void sim_mfma(
    const unsigned short* __restrict__ Zb, float* __restrict__ psum)
{
    const int t = threadIdx.x;
    const int wave = t >> 6, lane = t & 63;
    const int quad = lane >> 4, l15 = lane & 15;
    const int mbase = blockIdx.x * 128 + wave * 64;   // 64 rows per wave
    const int cs = blockIdx.y;                        // 0..NSPLIT-1
    const int cbase = cs * (N2 / NSPLIT);             // 256-col slice

    short8 a[4][4];
    #pragma unroll
    for (int at = 0; at < 4; ++at) {
        const short8* zra = (const short8*)(Zb + (size_t)(mbase + at * 16 + l15) * DOUT + quad * 8);
        #pragma unroll
        for (int kc = 0; kc < 4; ++kc) a[at][kc] = zra[kc * 4];
    }

    float rs[4][4];
    #pragma unroll
    for (int at = 0; at < 4; ++at)
        #pragma unroll
        for (int r = 0; r < 4; ++r) rs[at][r] = 0.f;

    short8 bcur[4], bnext[4];
    {
        const short8* zb = (const short8*)(Zb + (size_t)(cbase + l15) * DOUT + quad * 8);
        #pragma unroll
        for (int kc = 0; kc < 4; ++kc) bcur[kc] = zb[kc * 4];
    }

    #pragma unroll 1
    for (int nt = 0; nt < SIM_ITERS; ++nt) {
        const int cn = cbase + ((nt + 1) & (SIM_ITERS - 1)) * 16;
        const short8* zbn = (const short8*)(Zb + (size_t)(cn + l15) * DOUT + quad * 8);
        #pragma unroll
        for (int kc = 0; kc < 4; ++kc) bnext[kc] = zbn[kc * 4];

        floatx4 acc[4] = {{0.f,0.f,0.f,0.f},{0.f,0.f,0.f,0.f},
                          {0.f,0.f,0.f,0.f},{0.f,0.f,0.f,0.f}};
        #pragma unroll
        for (int kc = 0; kc < 4; ++kc)
            #pragma unroll
            for (int at = 0; at < 4; ++at)
                acc[at] = __builtin_amdgcn_mfma_f32_16x16x32_bf16(a[at][kc], bcur[kc], acc[at], 0, 0, 0);

        #pragma unroll
        for (int at = 0; at < 4; ++at)
            #pragma unroll
            for (int r = 0; r < 4; ++r)
                rs[at][r] += fast_exp2(acc[at][r]);

        #pragma unroll
        for (int kc = 0; kc < 4; ++kc) bcur[kc] = bnext[kc];
    }

    #pragma unroll
    for (int at = 0; at < 4; ++at) {
        const int gi0 = mbase + at * 16 + quad * 4;
        #pragma unroll
        for (int r = 0; r < 4; ++r) {
            float s = rs[at][r];
            s += __shfl_xor(s, 1);
            s += __shfl_xor(s, 2);
            s += __shfl_xor(s, 4);
            s += __shfl_xor(s, 8);
            if (l15 == 0) psum[(size_t)cs * N2 + gi0 + r] = s;
        }
    }
}

// ---- per-row lse - pos, minus diag term; block-reduce -> atomic loss ------
__global__ __launch_bounds__(256) void row_finalize(
    const unsigned short* __restrict__ Zb, const float* __restrict__ psum,
    float* __restrict__ out)
{
    int i = blockIdx.x * 256 + threadIdx.x;
    float s = 0.f;
    for (int cs = 0; cs < NSPLIT; ++cs) s += psum[(size_t)cs * N2 + i];
    int k = i & (NB - 1);
    const uint4* z1 = (const uint4*)(Zb + (size_t)k * DOUT);
    const uint4* z2 = (const uint4*)(Zb + (size_t)(k + NB) * DOUT);
    float d12 = 0.f, d11 = 0.f, d22 = 0.f;
    #pragma unroll
    for (int q = 0; q < 16; ++q) {
        uint4 a = z1[q], bqq = z2[q];
        const unsigned int aw[4] = {a.x, a.y, a.z, a.w};
        const unsigned int bw[4] = {bqq.x, bqq.y, bqq.z, bqq.w};
        #pragma unroll
        for (int c = 0; c < 4; ++c) {
            float alo = __uint_as_float(aw[c] << 16);
            float ahi = __uint_as_float(aw[c] & 0xffff0000u);
            float blo = __uint_as_float(bw[c] << 16);
            float bhi = __uint_as_float(bw[c] & 0xffff0000u);
            d12 += alo * blo + ahi * bhi;
            d11 += alo * alo + ahi * ahi;
            d22 += blo * blo + bhi * bhi;
        }
    }
    float dself = (i < NB) ? d11 : d22;
    // Zb is scaled: dot' = 2*log2(e)*dot => 2*dot = dot'*ln2; diag = exp2(dot')
    float rowval = logf(s - fast_exp2(dself)) - d12 * 0.69314718f;

    float r = rowval;
    r += __shfl_xor(r, 1);  r += __shfl_xor(r, 2);  r += __shfl_xor(r, 4);
    r += __shfl_xor(r, 8);  r += __shfl_xor(r, 16); r += __shfl_xor(r, 32);
    __shared__ float wsr[4];
    int lane = threadIdx.x & 63, w = threadIdx.x >> 6;
    if (lane == 0) wsr[w] = r;
    __syncthreads();
    if (threadIdx.x == 0)
        atomicAdd(out, (wsr[0] + wsr[1] + wsr[2] + wsr[3]) * (1.0f / N2));
}

extern "C" void kernel_launch(void* const* d_in, const int* in_sizes, int n_in,
                              void* d_out, int out_size, void* d_ws, size_t ws_size,
                              hipStream_t stream)
{
    const float* h1    = (const float*)d_in[0];
    const float* h2    = (const float*)d_in[1];
    const float* W1    = (const float*)d_in[2];
    const float* b1    = (const float*)d_in[3];
    const float* gamma = (const float*)d_in[4];
    const float* beta  = (const float*)d_in[5];
    const float* W2    = (const float*)d_in[6];
    const float* b2    = (const float*)d_in[7];
    float* out = (float*)d_out;

    float* ws      = (float*)d_ws;
    float* psumc   = ws;                            // 1024 f
    float* psqc    = psumc + 1024;                  // 1024 f (contiguous w/ psumc)
    unsigned short* W1b = (unsigned short*)(psqc + 1024);   // 98304 us
    unsigned short* W2b = W1b + DHID * DIN;         // 65536 us
    unsigned short* Ybf = W2b + DOUT * DHID;        // 8192*512 us = 8MB
    float* psum    = (float*)(Ybf + (size_t)N2 * DHID); // 32*8192 f = 1MB
    unsigned short* Zb = (unsigned short*)(psum + (size_t)NSPLIT * N2); // 2MB
    // total ~11.6 MB

    convert_w   <<<dim3(160),        256, 0, stream>>>(W1, W2, W1b, W2b, psumc, out);
    gemm1_mfma  <<<dim3(128, 8),     256, 0, stream>>>(h1, h2, W1b, b1, Ybf, psumc, psqc);
    gemm2_mfma  <<<dim3(512),       1024, 0, stream>>>(Ybf, W2b, psumc, psqc, gamma, beta, b2, Zb, out + 1);
    sim_mfma    <<<dim3(64, NSPLIT), 128, 0, stream>>>(Zb, psum);
    row_finalize<<<dim3(32),         256, 0, stream>>>(Zb, psum, out);
}

// Round 14
// 164.710 us; speedup vs baseline: 1.0889x; 1.0145x over previous
//
#include <hip/hip_runtime.h>

// SimCLR fused pipeline, round 14.
// sim: dist-2 prefetch (3 buffers b0/b1/b2, ROLLED 16-iter loop + explicit
//      copy-shift) -- doubles the load->use slack vs the dist-1 plateau (45us).
//      r6's 3-buffer failed only because it was fully unrolled (VGPR 192);
//      unroll-1 + copies is the shape the compiler keeps lean (r9/r11: 72-84).
// gemm1: (128,4) grid -- halves hidden h re-reads (96->48 MB fp32 from L3).
// convert_w (memset-fused), gemm2 (split-K x2), row_finalize: r13-proven.

#define NB   4096
#define DIN  192
#define DHID 512
#define DOUT 128
#define N2   8192   // 2*NB
#define NSPLIT 32   // sim col-splits; 256 cols per block
#define SIM_ITERS 16

typedef short short8 __attribute__((ext_vector_type(8)));   // 8 bf16 (4 VGPRs)
typedef float floatx4 __attribute__((ext_vector_type(4)));  // MFMA C/D frag

__device__ inline float fast_exp2(float x) {
#if __has_builtin(__builtin_amdgcn_exp2f)
    return __builtin_amdgcn_exp2f(x);
#else
    return exp2f(x);
#endif
}

__device__ inline unsigned short bf16_rne(float x) {
    unsigned int u = __float_as_uint(x);
    return (unsigned short)((u + 0x7fffu + ((u >> 16) & 1u)) >> 16);
}

// ------- convert W1, W2 -> bf16; block 0 also zeroes psumc/psqc/out --------
__global__ __launch_bounds__(256) void convert_w(
    const float* __restrict__ W1, const float* __restrict__ W2,
    unsigned short* __restrict__ W1b, unsigned short* __restrict__ W2b,
    float* __restrict__ psumc /* +psqc contiguous: 2048 floats */,
    float* __restrict__ out)
{
    const int NW1 = DHID * DIN / 4;   // 24576 float4
    const int NW2 = DOUT * DHID / 4;  // 16384 float4
    int id = blockIdx.x * 256 + threadIdx.x;
    if (blockIdx.x == 0) {
        for (int i = threadIdx.x; i < 2048; i += 256) psumc[i] = 0.f;
        if (threadIdx.x == 0) out[0] = 0.f;
    }
    const float* src; unsigned short* dst; int off;
    if (id < NW1)            { src = W1; dst = W1b; off = id; }
    else if (id < NW1 + NW2) { src = W2; dst = W2b; off = id - NW1; }
    else return;
    float4 x = ((const float4*)src)[off];
    unsigned int p0 = bf16_rne(x.x) | ((unsigned int)bf16_rne(x.y) << 16);
    unsigned int p1 = bf16_rne(x.z) | ((unsigned int)bf16_rne(x.w) << 16);
    ((uint2*)dst)[off] = make_uint2(p0, p1);
}

// ------- GEMM1 (bf16 MFMA): Ybf = [h1;h2] @ W1^T + b1, fused BN col-sums ---
// grid (128 m-blocks of 64 rows, 4 n-splits of 128 cols), 256 thr (4 waves).
// Wave: 16 rows x 128 cols (8 nt), K=192 (6 kc). h read fp32, cvt in-reg;
// 4 n-splits -> h re-read 4x (48 MB) instead of 8x (96 MB).
__global__ __launch_bounds__(256) void gemm1_mfma(
    const float* __restrict__ h1, const float* __restrict__ h2,
    const unsigned short* __restrict__ W1b, const float* __restrict__ b1,
    unsigned short* __restrict__ Ybf,
    float* __restrict__ psumc, float* __restrict__ psqc)
{
    const int t = threadIdx.x;
    const int wave = t >> 6, lane = t & 63;
    const int quad = lane >> 4, l15 = lane & 15;
    const int mb = blockIdx.x;
    const int m0 = mb * 64 + wave * 16;
    const int n0 = blockIdx.y * 128;
    const int v  = (mb >= 64);

    short8 a[6];
    {
        int row = m0 + l15;
        const float* hsrc = (row < NB) ? (h1 + (size_t)row * DIN)
                                       : (h2 + (size_t)(row - NB) * DIN);
        #pragma unroll
        for (int kc = 0; kc < 6; ++kc) {
            const float4* p = (const float4*)(hsrc + kc * 32 + quad * 8);
            float4 x0 = p[0], x1 = p[1];
            float xs[8] = {x0.x,x0.y,x0.z,x0.w,x1.x,x1.y,x1.z,x1.w};
            #pragma unroll
            for (int j = 0; j < 8; ++j) a[kc][j] = (short)bf16_rne(xs[j]);
        }
    }

    #pragma unroll 1
    for (int nt = 0; nt < 8; ++nt) {
        const int col = n0 + nt * 16 + l15;
        const short8* bptr = (const short8*)(W1b + (size_t)col * DIN + quad * 8);
        short8 b[6];
        #pragma unroll
        for (int kc = 0; kc < 6; ++kc) b[kc] = bptr[kc * 4];
        floatx4 acc = {0.f,0.f,0.f,0.f};
        #pragma unroll
        for (int kc = 0; kc < 6; ++kc)
            acc = __builtin_amdgcn_mfma_f32_16x16x32_bf16(a[kc], b[kc], acc, 0,0,0);
        const float bias = b1[col];
        float cs = 0.f, cq = 0.f;
        #pragma unroll
        for (int reg = 0; reg < 4; ++reg) {
            float y = acc[reg] + bias;
            int row = m0 + quad * 4 + reg;
            Ybf[(size_t)row * DHID + col] = bf16_rne(y);
            cs += y; cq += y * y;
        }
        cs += __shfl_xor(cs, 16); cs += __shfl_xor(cs, 32);
        cq += __shfl_xor(cq, 16); cq += __shfl_xor(cq, 32);
        if (quad == 0) {
            atomicAdd(psumc + v * DHID + col, cs);
            atomicAdd(psqc  + v * DHID + col, cq);
        }
    }
}

#define ZSCALE 1.6986436f   // sqrt(2*log2(e)); Zb = z*ZSCALE so dot = exp2 arg

// ---- GEMM2 (bf16 MFMA, split-K x2): z = relu(bn(Y)) @ W2^T + b2, L2-norm --
// 16 waves/block (1024 thr): wave w -> col-group (w&7), K-half (w>>3).
// Each wave: 8 rolled iters (dist-1 prefetch). K-halves combined via LDS.
__global__ __launch_bounds__(1024) void gemm2_mfma(
    const unsigned short* __restrict__ Ybf, const unsigned short* __restrict__ W2b,
    const float* __restrict__ psumc, const float* __restrict__ psqc,
    const float* __restrict__ gamma, const float* __restrict__ beta,
    const float* __restrict__ b2,
    unsigned short* __restrict__ Zb, float* __restrict__ outz)
{
    __shared__ float sc_sh[DHID], sh_sh[DHID];
    __shared__ __align__(16) float acc_lds[8][64][4];   // upper-half partials
    __shared__ float sq_lds[8][16];
    const int t = threadIdx.x;
    const int wave = t >> 6, lane = t & 63;
    const int quad = lane >> 4, l15 = lane & 15;
    const int cg = wave & 7, kh = wave >> 3;
    const int mtbase = blockIdx.x * 16;
    const int v = (mtbase >= NB);
    const int col = cg * 16 + l15;

    if (t < DHID) {   // bn finalize: 512 threads cover 512 cols
        int c = t;
        float mean = psumc[v * DHID + c] * (1.0f / NB);
        float var  = psqc [v * DHID + c] * (1.0f / NB) - mean * mean;
        float rstd = rsqrtf(var + 1e-5f);
        float scv = gamma[c] * rstd;
        sc_sh[c] = scv;
        sh_sh[c] = beta[c] - mean * scv;
    }
    __syncthreads();

    const int kbase = kh * 8;   // this wave's 8 k-chunks
    const unsigned short* yrow = Ybf + (size_t)(mtbase + l15) * DHID + kbase * 32 + quad * 8;
    const unsigned short* wcol = W2b + (size_t)col * DHID + kbase * 32 + quad * 8;

    uint4 ycur = *(const uint4*)yrow;
    short8 bcur = *(const short8*)wcol;
    floatx4 acc = {0.f, 0.f, 0.f, 0.f};

    #pragma unroll 1
    for (int kc = 0; kc < 8; ++kc) {
        const int kn = (kc + 1) & 7;          // wraps on last iter (unused)
        uint4 ynext = *(const uint4*)(yrow + kn * 32);
        short8 bnext = *(const short8*)(wcol + kn * 32);

        const int k = (kbase + kc) * 32 + quad * 8;
        const float4 s0 = *(const float4*)&sc_sh[k], s1 = *(const float4*)&sc_sh[k + 4];
        const float4 h0 = *(const float4*)&sh_sh[k], h1v = *(const float4*)&sh_sh[k + 4];
        const unsigned int yw[4] = {ycur.x, ycur.y, ycur.z, ycur.w};
        float xs[8];
        #pragma unroll
        for (int c2 = 0; c2 < 4; ++c2) {
            xs[c2 * 2]     = __uint_as_float(yw[c2] << 16);
            xs[c2 * 2 + 1] = __uint_as_float(yw[c2] & 0xffff0000u);
        }
        const float ss[8] = {s0.x,s0.y,s0.z,s0.w,s1.x,s1.y,s1.z,s1.w};
        const float hh[8] = {h0.x,h0.y,h0.z,h0.w,h1v.x,h1v.y,h1v.z,h1v.w};
        short8 afr;
        #pragma unroll
        for (int j = 0; j < 8; ++j)
            afr[j] = (short)bf16_rne(fmaxf(xs[j] * ss[j] + hh[j], 0.f));
        acc = __builtin_amdgcn_mfma_f32_16x16x32_bf16(afr, bcur, acc, 0,0,0);
        ycur = ynext; bcur = bnext;
    }

    if (kh == 1) {   // upper half: publish partials
        #pragma unroll
        for (int reg = 0; reg < 4; ++reg) acc_lds[cg][lane][reg] = acc[reg];
    }
    __syncthreads();
    if (kh == 1) return;

    const float bias = b2[col];
    float zv[4];
    #pragma unroll
    for (int reg = 0; reg < 4; ++reg) {
        zv[reg] = acc[reg] + acc_lds[cg][lane][reg] + bias;
        float q = zv[reg] * zv[reg];
        q += __shfl_xor(q, 1); q += __shfl_xor(q, 2);
        q += __shfl_xor(q, 4); q += __shfl_xor(q, 8);
        if (l15 == 0) sq_lds[cg][quad * 4 + reg] = q;
    }
    __syncthreads();
    #pragma unroll
    for (int reg = 0; reg < 4; ++reg) {
        float tot = 0.f;
        #pragma unroll
        for (int w = 0; w < 8; ++w) tot += sq_lds[w][quad * 4 + reg];
        float inv = 1.0f / fmaxf(sqrtf(tot), 1e-12f);
        const int row = mtbase + quad * 4 + reg;
        float z = zv[reg] * inv;
        outz[(size_t)row * DOUT + col] = z;
        Zb[(size_t)row * DOUT + col] = bf16_rne(z * ZSCALE);
    }
}

// ---- sim: psum_row = sum_cols exp2(Zb . Zb^T)  (diag included; subtracted
// in row_finalize). Wave owns 64 rows (4 A-tiles in regs). ROLLED 16-iter
// loop, DIST-2 prefetch: 3 buffers b0/b1/b2 + copy-shift (slack = 2 iters
// > L2 latency; dist-1's 1-iter slack was the 45us plateau).
// grid (32, NSPLIT=32) x 256 thr.
__global__ __launch_bounds__(256) void sim_mfma(
    const unsigned short* __restrict__ Zb, float* __restrict__ psum)
{
    const int t = threadIdx.x;
    const int wave = t >> 6, lane = t & 63;
    const int quad = lane >> 4, l15 = lane & 15;
    const int mbase = blockIdx.x * 256 + wave * 64;   // 64 rows per wave
    const int cs = blockIdx.y;                        // 0..NSPLIT-1
    const int cbase = cs * (N2 / NSPLIT);             // 256-col slice

    short8 a[4][4];
    #pragma unroll
    for (int at = 0; at < 4; ++at) {
        const short8* zra = (const short8*)(Zb + (size_t)(mbase + at * 16 + l15) * DOUT + quad * 8);
        #pragma unroll
        for (int kc = 0; kc < 4; ++kc) a[at][kc] = zra[kc * 4];
    }

    float rs[4][4];
    #pragma unroll
    for (int at = 0; at < 4; ++at)
        #pragma unroll
        for (int r = 0; r < 4; ++r) rs[at][r] = 0.f;

    // per-lane B pointer; tile nt is at offset nt*256 short8 (16 rows x 128)
    const short8* zb = (const short8*)(Zb + (size_t)(cbase + l15) * DOUT + quad * 8);
    short8 b0[4], b1[4], b2[4];
    #pragma unroll
    for (int kc = 0; kc < 4; ++kc) b0[kc] = zb[kc * 4];          // tile 0
    #pragma unroll
    for (int kc = 0; kc < 4; ++kc) b1[kc] = zb[256 + kc * 4];    // tile 1

    #pragma unroll 1
    for (int nt = 0; nt < SIM_ITERS; ++nt) {
        const int cn = ((nt + 2) & (SIM_ITERS - 1)) * 256;   // dist-2 (wraps, unused)
        #pragma unroll
        for (int kc = 0; kc < 4; ++kc) b2[kc] = zb[cn + kc * 4];

        floatx4 acc[4] = {{0.f,0.f,0.f,0.f},{0.f,0.f,0.f,0.f},
                          {0.f,0.f,0.f,0.f},{0.f,0.f,0.f,0.f}};
        #pragma unroll
        for (int kc = 0; kc < 4; ++kc)
            #pragma unroll
            for (int at = 0; at < 4; ++at)
                acc[at] = __builtin_amdgcn_mfma_f32_16x16x32_bf16(a[at][kc], b0[kc], acc[at], 0, 0, 0);

        #pragma unroll
        for (int at = 0; at < 4; ++at)
            #pragma unroll
            for (int r = 0; r < 4; ++r)
                rs[at][r] += fast_exp2(acc[at][r]);

        #pragma unroll
        for (int kc = 0; kc < 4; ++kc) { b0[kc] = b1[kc]; b1[kc] = b2[kc]; }
    }

    #pragma unroll
    for (int at = 0; at < 4; ++at) {
        const int gi0 = mbase + at * 16 + quad * 4;
        #pragma unroll
        for (int r = 0; r < 4; ++r) {
            float s = rs[at][r];
            s += __shfl_xor(s, 1);
            s += __shfl_xor(s, 2);
            s += __shfl_xor(s, 4);
            s += __shfl_xor(s, 8);
            if (l15 == 0) psum[(size_t)cs * N2 + gi0 + r] = s;
        }
    }
}

// ---- per-row lse - pos, minus diag term; block-reduce -> atomic loss ------
__global__ __launch_bounds__(256) void row_finalize(
    const unsigned short* __restrict__ Zb, const float* __restrict__ psum,
    float* __restrict__ out)
{
    int i = blockIdx.x * 256 + threadIdx.x;
    float s = 0.f;
    for (int cs = 0; cs < NSPLIT; ++cs) s += psum[(size_t)cs * N2 + i];
    int k = i & (NB - 1);
    const uint4* z1 = (const uint4*)(Zb + (size_t)k * DOUT);
    const uint4* z2 = (const uint4*)(Zb + (size_t)(k + NB) * DOUT);
    float d12 = 0.f, d11 = 0.f, d22 = 0.f;
    #pragma unroll
    for (int q = 0; q < 16; ++q) {
        uint4 a = z1[q], bqq = z2[q];
        const unsigned int aw[4] = {a.x, a.y, a.z, a.w};
        const unsigned int bw[4] = {bqq.x, bqq.y, bqq.z, bqq.w};
        #pragma unroll
        for (int c = 0; c < 4; ++c) {
            float alo = __uint_as_float(aw[c] << 16);
            float ahi = __uint_as_float(aw[c] & 0xffff0000u);
            float blo = __uint_as_float(bw[c] << 16);
            float bhi = __uint_as_float(bw[c] & 0xffff0000u);
            d12 += alo * blo + ahi * bhi;
            d11 += alo * alo + ahi * ahi;
            d22 += blo * blo + bhi * bhi;
        }
    }
    float dself = (i < NB) ? d11 : d22;
    // Zb is scaled: dot' = 2*log2(e)*dot => 2*dot = dot'*ln2; diag = exp2(dot')
    float rowval = logf(s - fast_exp2(dself)) - d12 * 0.69314718f;

    float r = rowval;
    r += __shfl_xor(r, 1);  r += __shfl_xor(r, 2);  r += __shfl_xor(r, 4);
    r += __shfl_xor(r, 8);  r += __shfl_xor(r, 16); r += __shfl_xor(r, 32);
    __shared__ float wsr[4];
    int lane = threadIdx.x & 63, w = threadIdx.x >> 6;
    if (lane == 0) wsr[w] = r;
    __syncthreads();
    if (threadIdx.x == 0)
        atomicAdd(out, (wsr[0] + wsr[1] + wsr[2] + wsr[3]) * (1.0f / N2));
}

extern "C" void kernel_launch(void* const* d_in, const int* in_sizes, int n_in,
                              void* d_out, int out_size, void* d_ws, size_t ws_size,
                              hipStream_t stream)
{
    const float* h1    = (const float*)d_in[0];
    const float* h2    = (const float*)d_in[1];
    const float* W1    = (const float*)d_in[2];
    const float* b1    = (const float*)d_in[3];
    const float* gamma = (const float*)d_in[4];
    const float* beta  = (const float*)d_in[5];
    const float* W2    = (const float*)d_in[6];
    const float* b2    = (const float*)d_in[7];
    float* out = (float*)d_out;

    float* ws      = (float*)d_ws;
    float* psumc   = ws;                            // 1024 f
    float* psqc    = psumc + 1024;                  // 1024 f (contiguous w/ psumc)
    unsigned short* W1b = (unsigned short*)(psqc + 1024);   // 98304 us
    unsigned short* W2b = W1b + DHID * DIN;         // 65536 us
    unsigned short* Ybf = W2b + DOUT * DHID;        // 8192*512 us = 8MB
    float* psum    = (float*)(Ybf + (size_t)N2 * DHID); // 32*8192 f = 1MB
    unsigned short* Zb = (unsigned short*)(psum + (size_t)NSPLIT * N2); // 2MB
    // total ~11.6 MB

    convert_w   <<<dim3(160),        256, 0, stream>>>(W1, W2, W1b, W2b, psumc, out);
    gemm1_mfma  <<<dim3(128, 4),     256, 0, stream>>>(h1, h2, W1b, b1, Ybf, psumc, psqc);
    gemm2_mfma  <<<dim3(512),       1024, 0, stream>>>(Ybf, W2b, psumc, psqc, gamma, beta, b2, Zb, out + 1);
    sim_mfma    <<<dim3(32, NSPLIT), 256, 0, stream>>>(Zb, psum);
    row_finalize<<<dim3(32),         256, 0, stream>>>(Zb, psum, out);
}